// Round 1
// baseline (269.429 us; speedup 1.0000x reference)
//
#include <hip/hip_runtime.h>
#include <math.h>

#define HH 32

__device__ __forceinline__ float leaky(float x) { return x >= 0.0f ? x : 0.01f * x; }

__global__ __launch_bounds__(256) void aero_fused(
    const float* __restrict__ vin, const float* __restrict__ win,
    const float* __restrict__ gW1, const float* __restrict__ gb1,
    const float* __restrict__ gW2, const float* __restrict__ gb2,
    const float* __restrict__ gWd1, const float* __restrict__ gbd1,
    const float* __restrict__ gWd2, const float* __restrict__ gbd2,
    const float* __restrict__ gbias,
    float* __restrict__ out, int nrows)
{
    __shared__ float sW1[HH * 3];
    __shared__ float sb1[HH];
    __shared__ float sW2[HH * HH];
    __shared__ float sb2[HH];
    __shared__ float sWd1[HH * HH];
    __shared__ float sbd1[HH];
    __shared__ float sWd2[3 * HH];
    __shared__ float sbd2[3];
    __shared__ float sbias[3];

    const int t = threadIdx.x;

    // Cooperative staging of all weights (~2342 floats) into LDS.
    if (t < HH * 3) sW1[t] = gW1[t];
    if (t < HH)     sb1[t] = gb1[t];
    for (int i = t; i < HH * HH; i += 256) {
        sW2[i]  = gW2[i];
        sWd1[i] = gWd1[i];
    }
    if (t < HH)     { sb2[t] = gb2[t]; sbd1[t] = gbd1[t]; }
    if (t < 3 * HH) sWd2[t] = gWd2[t];
    if (t < 3)      { sbd2[t] = gbd2[t]; sbias[t] = gbias[t]; }
    __syncthreads();

    const int row = blockIdx.x * 256 + t;
    if (row >= nrows) return;

    const float v0 = vin[3 * row + 0], v1 = vin[3 * row + 1], v2 = vin[3 * row + 2];
    const float w0 = win[3 * row + 0], w1 = win[3 * row + 1], w2 = win[3 * row + 2];

    // ---- Gram-Schmidt ----
    const float nv  = sqrtf(v0 * v0 + v1 * v1 + v2 * v2) + 1e-8f;
    const float rnv = 1.0f / nv;
    const float a0 = v0 * rnv, a1 = v1 * rnv, a2 = v2 * rnv;      // v_on
    const float proj = w0 * a0 + w1 * a1 + w2 * a2;                // w . v_on
    const float o0 = w0 - proj * a0, o1 = w1 - proj * a1, o2 = w2 - proj * a2;
    const float nw  = sqrtf(o0 * o0 + o1 * o1 + o2 * o2) + 1e-8f;
    const float rnw = 1.0f / nw;
    const float c0 = o0 * rnw, c1 = o1 * rnw, c2 = o2 * rnw;       // w_on
    const float u0 = a1 * c2 - a2 * c1;                            // u_on = v_on x w_on
    const float u1 = a2 * c0 - a0 * c2;
    const float u2 = a0 * c1 - a1 * c0;

    // feat = [v.v_on, w.v_on, w.w_on]
    const float f0 = v0 * a0 + v1 * a1 + v2 * a2;
    const float f1 = proj;
    const float f2 = w0 * c0 + w1 * c1 + w2 * c2;

    // ---- layer 1: 3 -> 32 ----
    float h1[HH];
    #pragma unroll
    for (int j = 0; j < HH; ++j) {
        float acc = sb1[j];
        acc = fmaf(sW1[3 * j + 0], f0, acc);
        acc = fmaf(sW1[3 * j + 1], f1, acc);
        acc = fmaf(sW1[3 * j + 2], f2, acc);
        h1[j] = leaky(acc);
    }

    // ---- layer 2: 32 -> 32, gated by h1 ----
    float h2[HH];
    #pragma unroll
    for (int j = 0; j < HH; ++j) {
        float acc = sb2[j];
        #pragma unroll
        for (int k = 0; k < HH; ++k) acc = fmaf(sW2[HH * j + k], h1[k], acc);
        h2[j] = leaky(acc) * h1[j];
    }

    // ---- layer 3: 32 -> 32 ----
    float h3[HH];
    #pragma unroll
    for (int j = 0; j < HH; ++j) {
        float acc = sbd1[j];
        #pragma unroll
        for (int k = 0; k < HH; ++k) acc = fmaf(sWd1[HH * j + k], h2[k], acc);
        h3[j] = leaky(acc);
    }

    // ---- layer 4: 32 -> 3 ----
    float y0 = sbd2[0], y1 = sbd2[1], y2 = sbd2[2];
    #pragma unroll
    for (int k = 0; k < HH; ++k) {
        y0 = fmaf(sWd2[0 * HH + k], h3[k], y0);
        y1 = fmaf(sWd2[1 * HH + k], h3[k], y1);
        y2 = fmaf(sWd2[2 * HH + k], h3[k], y2);
    }

    // ---- out = R @ y + bias;  R columns are (v_on, w_on, u_on) ----
    out[3 * row + 0] = fmaf(a0, y0, fmaf(c0, y1, fmaf(u0, y2, sbias[0])));
    out[3 * row + 1] = fmaf(a1, y0, fmaf(c1, y1, fmaf(u1, y2, sbias[1])));
    out[3 * row + 2] = fmaf(a2, y0, fmaf(c2, y1, fmaf(u2, y2, sbias[2])));
}

extern "C" void kernel_launch(void* const* d_in, const int* in_sizes, int n_in,
                              void* d_out, int out_size, void* d_ws, size_t ws_size,
                              hipStream_t stream) {
    const float* v    = (const float*)d_in[0];
    const float* w    = (const float*)d_in[1];
    const float* W1   = (const float*)d_in[2];
    const float* b1   = (const float*)d_in[3];
    const float* W2   = (const float*)d_in[4];
    const float* b2   = (const float*)d_in[5];
    const float* Wd1  = (const float*)d_in[6];
    const float* bd1  = (const float*)d_in[7];
    const float* Wd2  = (const float*)d_in[8];
    const float* bd2  = (const float*)d_in[9];
    const float* bias = (const float*)d_in[10];

    const int nrows = in_sizes[0] / 3;
    dim3 block(256);
    dim3 grid((nrows + 255) / 256);
    hipLaunchKernelGGL(aero_fused, grid, block, 0, stream,
                       v, w, W1, b1, W2, b2, Wd1, bd1, Wd2, bd2, bias,
                       (float*)d_out, nrows);
}

// Round 2
// 195.948 us; speedup vs baseline: 1.3750x; 1.3750x over previous
//
#include <hip/hip_runtime.h>
#include <math.h>

typedef float v2f __attribute__((ext_vector_type(2)));

__device__ __forceinline__ float leaky(float x) { return x >= 0.0f ? x : 0.01f * x; }

__global__ __launch_bounds__(256, 4) void aero_fused(
    const float* __restrict__ vin, const float* __restrict__ win,
    const float* __restrict__ gW1, const float* __restrict__ gb1,
    const float* __restrict__ gW2, const float* __restrict__ gb2,
    const float* __restrict__ gWd1, const float* __restrict__ gbd1,
    const float* __restrict__ gWd2, const float* __restrict__ gbd2,
    const float* __restrict__ gbias,
    float* __restrict__ out, int nrows)
{
    const int row = blockIdx.x * 256 + threadIdx.x;
    if (row >= nrows) return;

    const float v0 = vin[3 * row + 0], v1 = vin[3 * row + 1], v2 = vin[3 * row + 2];
    const float w0 = win[3 * row + 0], w1 = win[3 * row + 1], w2 = win[3 * row + 2];

    // ---- Gram-Schmidt (fp32, per-lane) ----
    const float nv  = sqrtf(v0 * v0 + v1 * v1 + v2 * v2) + 1e-8f;
    const float rnv = 1.0f / nv;
    const float a0 = v0 * rnv, a1 = v1 * rnv, a2 = v2 * rnv;      // v_on
    const float proj = w0 * a0 + w1 * a1 + w2 * a2;                // w . v_on
    const float o0 = w0 - proj * a0, o1 = w1 - proj * a1, o2 = w2 - proj * a2;
    const float nw  = sqrtf(o0 * o0 + o1 * o1 + o2 * o2) + 1e-8f;
    const float rnw = 1.0f / nw;
    const float c0 = o0 * rnw, c1 = o1 * rnw, c2 = o2 * rnw;       // w_on
    const float u0 = a1 * c2 - a2 * c1;                            // u_on
    const float u1 = a2 * c0 - a0 * c2;
    const float u2 = a0 * c1 - a1 * c0;

    const float f0 = v0 * a0 + v1 * a1 + v2 * a2;
    const float f1 = proj;
    const float f2 = w0 * c0 + w1 * c1 + w2 * c2;

    // ---- layer 1: 3 -> 32 (weights via scalar loads; constant indices) ----
    v2f h1v[16];
    #pragma unroll
    for (int j2 = 0; j2 < 16; ++j2) {
        #pragma unroll
        for (int c = 0; c < 2; ++c) {
            const int j = 2 * j2 + c;
            float acc = gb1[j];
            acc = fmaf(gW1[3 * j + 0], f0, acc);
            acc = fmaf(gW1[3 * j + 1], f1, acc);
            acc = fmaf(gW1[3 * j + 2], f2, acc);
            h1v[j2][c] = leaky(acc);
        }
    }

    // ---- layer 2: 32 -> 32, gated by h1 (packed fp32 reduction) ----
    const v2f* W2v = (const v2f*)gW2;   // row j: W2v[j*16 + k2]
    v2f h2v[16];
    #pragma unroll
    for (int j = 0; j < 32; ++j) {
        v2f acc = {0.0f, 0.0f};
        #pragma unroll
        for (int k2 = 0; k2 < 16; ++k2)
            acc = __builtin_elementwise_fma(W2v[j * 16 + k2], h1v[k2], acc);
        const float s = acc.x + acc.y + gb2[j];
        h2v[j >> 1][j & 1] = leaky(s) * h1v[j >> 1][j & 1];
    }

    // ---- layer 3: 32 -> 32 ----
    const v2f* Wd1v = (const v2f*)gWd1;
    v2f h3v[16];
    #pragma unroll
    for (int j = 0; j < 32; ++j) {
        v2f acc = {0.0f, 0.0f};
        #pragma unroll
        for (int k2 = 0; k2 < 16; ++k2)
            acc = __builtin_elementwise_fma(Wd1v[j * 16 + k2], h2v[k2], acc);
        const float s = acc.x + acc.y + gbd1[j];
        h3v[j >> 1][j & 1] = leaky(s);
    }

    // ---- layer 4: 32 -> 3 ----
    const v2f* Wd2v = (const v2f*)gWd2;
    float y[3];
    #pragma unroll
    for (int i = 0; i < 3; ++i) {
        v2f acc = {0.0f, 0.0f};
        #pragma unroll
        for (int k2 = 0; k2 < 16; ++k2)
            acc = __builtin_elementwise_fma(Wd2v[i * 16 + k2], h3v[k2], acc);
        y[i] = acc.x + acc.y + gbd2[i];
    }

    // ---- out = R @ y + bias;  R columns are (v_on, w_on, u_on) ----
    out[3 * row + 0] = fmaf(a0, y[0], fmaf(c0, y[1], fmaf(u0, y[2], gbias[0])));
    out[3 * row + 1] = fmaf(a1, y[0], fmaf(c1, y[1], fmaf(u1, y[2], gbias[1])));
    out[3 * row + 2] = fmaf(a2, y[0], fmaf(c2, y[1], fmaf(u2, y[2], gbias[2])));
}

extern "C" void kernel_launch(void* const* d_in, const int* in_sizes, int n_in,
                              void* d_out, int out_size, void* d_ws, size_t ws_size,
                              hipStream_t stream) {
    const float* v    = (const float*)d_in[0];
    const float* w    = (const float*)d_in[1];
    const float* W1   = (const float*)d_in[2];
    const float* b1   = (const float*)d_in[3];
    const float* W2   = (const float*)d_in[4];
    const float* b2   = (const float*)d_in[5];
    const float* Wd1  = (const float*)d_in[6];
    const float* bd1  = (const float*)d_in[7];
    const float* Wd2  = (const float*)d_in[8];
    const float* bd2  = (const float*)d_in[9];
    const float* bias = (const float*)d_in[10];

    const int nrows = in_sizes[0] / 3;
    dim3 block(256);
    dim3 grid((nrows + 255) / 256);
    hipLaunchKernelGGL(aero_fused, grid, block, 0, stream,
                       v, w, W1, b1, W2, b2, Wd1, bd1, Wd2, bd2, bias,
                       (float*)d_out, nrows);
}

// Round 3
// 143.226 us; speedup vs baseline: 1.8811x; 1.3681x over previous
//
#include <hip/hip_runtime.h>
#include <math.h>

typedef __attribute__((ext_vector_type(8))) short short8;
typedef __attribute__((ext_vector_type(4))) float f32x4;
typedef __attribute__((ext_vector_type(4))) unsigned int u32x4;
typedef __attribute__((ext_vector_type(2))) unsigned long long u64x2;

static __device__ __forceinline__ unsigned int fbits(float f) {
    union { float f; unsigned int u; } v; v.f = f; return v.u;
}
static __device__ __forceinline__ float bitsf(unsigned int u) {
    union { float f; unsigned int u; } v; v.u = u; return v.f;
}
// pack two f32 -> bf16 pair (truncation; activations ~1e-4, threshold 0.196 -> safe)
static __device__ __forceinline__ unsigned int pkbf(float lo, float hi) {
    return (fbits(hi) & 0xFFFF0000u) | (fbits(lo) >> 16);
}
static __device__ __forceinline__ float bflo(unsigned int u) { return bitsf(u << 16); }
static __device__ __forceinline__ float bfhi(unsigned int u) { return bitsf(u & 0xFFFF0000u); }
// leaky = max(x, 0.01x): exact for both signs, 2 VALU ops
static __device__ __forceinline__ float leaky(float x) { return fmaxf(x, 0.01f * x); }

// LDS row layout: 32 bf16 per row, k-interleaved: u32 index c holds (k=c) in lo16,
// (k=c+16) in hi16. Row stride = 9 ulongs (72 B, odd multiple of 8 B -> 2-way max
// bank aliasing on b64/b32 ops = free). A-frag for MFMA = 16 contiguous bytes at
// ulong offset 2*quad; the k-permutation pos=2*(k&15)+(k>>4) is applied identically
// to the B fragments, so the MFMA reduction is consistent.

__global__ __launch_bounds__(256, 4) void aero_mfma(
    const float* __restrict__ vin, const float* __restrict__ win,
    const float* __restrict__ gW1, const float* __restrict__ gb1,
    const float* __restrict__ gW2, const float* __restrict__ gb2,
    const float* __restrict__ gWd1, const float* __restrict__ gbd1,
    const float* __restrict__ gWd2, const float* __restrict__ gbd2,
    const float* __restrict__ gbias,
    float* __restrict__ out, int nrows)
{
    __shared__ unsigned long long hbuf[256 * 9];  // h1, later h2
    __shared__ unsigned long long zbuf[256 * 9];  // z2, later z3
    unsigned int* const z32 = (unsigned int*)zbuf;

    const int tid = threadIdx.x;
    int row = blockIdx.x * 256 + tid;
    if (row >= nrows) row = nrows - 1;   // benign duplicate work; keeps barriers uniform

    const int i15   = tid & 15;          // n within n-tile / m within m-tile
    const int quad  = (tid >> 4) & 3;    // k-chunk selector
    const int wbase = tid & 192;         // this wave's 64-row LDS window

    // ---- per-lane B fragments (weights, k-permuted) + bias for both MFMA layers ----
    unsigned int bw2[2][4], bwd1[2][4];
    float b2v[2], bd1v[2];
    #pragma unroll
    for (int u = 0; u < 2; ++u) {
        const int n = u * 16 + i15;
        const float* p2 = gW2  + n * 32 + 4 * quad;
        const float* p3 = gWd1 + n * 32 + 4 * quad;
        #pragma unroll
        for (int j = 0; j < 4; ++j) {
            bw2[u][j]  = pkbf(p2[j], p2[j + 16]);   // bf16 pair (k=4q+j, k=4q+j+16)
            bwd1[u][j] = pkbf(p3[j], p3[j + 16]);
        }
        b2v[u]  = gb2[n];
        bd1v[u] = gbd1[n];
    }

    // ---- phase A: Gram-Schmidt + layer 1 (per-lane, lane = row) ----
    const float v0 = vin[3 * row + 0], v1 = vin[3 * row + 1], v2 = vin[3 * row + 2];
    const float w0 = win[3 * row + 0], w1 = win[3 * row + 1], w2 = win[3 * row + 2];

    const float nv  = sqrtf(v0 * v0 + v1 * v1 + v2 * v2) + 1e-8f;
    const float rnv = 1.0f / nv;
    const float a0 = v0 * rnv, a1 = v1 * rnv, a2 = v2 * rnv;       // v_on
    const float proj = w0 * a0 + w1 * a1 + w2 * a2;
    const float o0 = w0 - proj * a0, o1 = w1 - proj * a1, o2 = w2 - proj * a2;
    const float nw  = sqrtf(o0 * o0 + o1 * o1 + o2 * o2) + 1e-8f;
    const float rnw = 1.0f / nw;
    const float c0 = o0 * rnw, c1 = o1 * rnw, c2 = o2 * rnw;       // w_on
    const float u0 = a1 * c2 - a2 * c1;                            // u_on
    const float u1 = a2 * c0 - a0 * c2;
    const float u2 = a0 * c1 - a1 * c0;

    const float f0 = v0 * a0 + v1 * a1 + v2 * a2;
    const float f1 = proj;
    const float f2 = w0 * c0 + w1 * c1 + w2 * c2;

    float h1[32];
    #pragma unroll
    for (int j = 0; j < 32; ++j) {
        float acc = gb1[j];
        acc = fmaf(gW1[3 * j + 0], f0, acc);
        acc = fmaf(gW1[3 * j + 1], f1, acc);
        acc = fmaf(gW1[3 * j + 2], f2, acc);
        h1[j] = leaky(acc);
    }

    // pack h1 (k-interleaved) and write this lane's row
    {
        unsigned long long* dst = hbuf + tid * 9;
        #pragma unroll
        for (int c2 = 0; c2 < 8; ++c2) {
            const unsigned int lo = pkbf(h1[2 * c2],     h1[2 * c2 + 16]);
            const unsigned int hi = pkbf(h1[2 * c2 + 1], h1[2 * c2 + 17]);
            dst[c2] = (unsigned long long)lo | ((unsigned long long)hi << 32);
        }
    }

    // ---- phase B: layer 2 as MFMA (z2 = h1 @ W2^T + b2), write C-layout packed ----
    __syncthreads();
    {
        const short8 bf0 = __builtin_bit_cast(short8, (u32x4){bw2[0][0], bw2[0][1], bw2[0][2], bw2[0][3]});
        const short8 bf1 = __builtin_bit_cast(short8, (u32x4){bw2[1][0], bw2[1][1], bw2[1][2], bw2[1][3]});
        #pragma unroll
        for (int t = 0; t < 4; ++t) {
            const int ra = wbase + 16 * t + i15;
            u64x2 av;
            av.x = hbuf[ra * 9 + 2 * quad];
            av.y = hbuf[ra * 9 + 2 * quad + 1];
            const short8 af = __builtin_bit_cast(short8, av);
            f32x4 acc0 = {b2v[0], b2v[0], b2v[0], b2v[0]};
            f32x4 acc1 = {b2v[1], b2v[1], b2v[1], b2v[1]};
            acc0 = __builtin_amdgcn_mfma_f32_16x16x32_bf16(af, bf0, acc0, 0, 0, 0);
            acc1 = __builtin_amdgcn_mfma_f32_16x16x32_bf16(af, bf1, acc1, 0, 0, 0);
            const int zr = wbase + 16 * t + 4 * quad;
            #pragma unroll
            for (int r = 0; r < 4; ++r)
                z32[(zr + r) * 18 + i15] = pkbf(acc0[r], acc1[r]);  // cols (i15, i15+16)
        }
    }

    // ---- phase C: transpose z2 back (lane = row), gate with in-register h1, write h2 ----
    __syncthreads();
    {
        const unsigned long long* src = zbuf + tid * 9;
        unsigned long long* dst = hbuf + tid * 9;
        #pragma unroll
        for (int c2 = 0; c2 < 8; ++c2) {
            const unsigned long long zz = src[c2];
            const unsigned int ulo = (unsigned int)zz;
            const unsigned int uhi = (unsigned int)(zz >> 32);
            const float g0 = leaky(bflo(ulo)) * h1[2 * c2];
            const float g1 = leaky(bfhi(ulo)) * h1[2 * c2 + 16];
            const float g2 = leaky(bflo(uhi)) * h1[2 * c2 + 1];
            const float g3 = leaky(bfhi(uhi)) * h1[2 * c2 + 17];
            const unsigned int lo = pkbf(g0, g1);
            const unsigned int hi = pkbf(g2, g3);
            dst[c2] = (unsigned long long)lo | ((unsigned long long)hi << 32);
        }
    }

    // ---- phase D: layer 3 as MFMA (z3 = h2 @ Wd1^T + bd1) ----
    __syncthreads();
    {
        const short8 bf0 = __builtin_bit_cast(short8, (u32x4){bwd1[0][0], bwd1[0][1], bwd1[0][2], bwd1[0][3]});
        const short8 bf1 = __builtin_bit_cast(short8, (u32x4){bwd1[1][0], bwd1[1][1], bwd1[1][2], bwd1[1][3]});
        #pragma unroll
        for (int t = 0; t < 4; ++t) {
            const int ra = wbase + 16 * t + i15;
            u64x2 av;
            av.x = hbuf[ra * 9 + 2 * quad];
            av.y = hbuf[ra * 9 + 2 * quad + 1];
            const short8 af = __builtin_bit_cast(short8, av);
            f32x4 acc0 = {bd1v[0], bd1v[0], bd1v[0], bd1v[0]};
            f32x4 acc1 = {bd1v[1], bd1v[1], bd1v[1], bd1v[1]};
            acc0 = __builtin_amdgcn_mfma_f32_16x16x32_bf16(af, bf0, acc0, 0, 0, 0);
            acc1 = __builtin_amdgcn_mfma_f32_16x16x32_bf16(af, bf1, acc1, 0, 0, 0);
            const int zr = wbase + 16 * t + 4 * quad;
            #pragma unroll
            for (int r = 0; r < 4; ++r)
                z32[(zr + r) * 18 + i15] = pkbf(acc0[r], acc1[r]);
        }
    }

    // ---- phase E: leaky(z3) per-lane, layer 4 (32->3, scalar weights), rotate, store ----
    __syncthreads();
    {
        const unsigned long long* src = zbuf + tid * 9;
        float h3[32];
        #pragma unroll
        for (int c2 = 0; c2 < 8; ++c2) {
            const unsigned long long zz = src[c2];
            const unsigned int ulo = (unsigned int)zz;
            const unsigned int uhi = (unsigned int)(zz >> 32);
            h3[2 * c2]      = leaky(bflo(ulo));
            h3[2 * c2 + 16] = leaky(bfhi(ulo));
            h3[2 * c2 + 1]  = leaky(bflo(uhi));
            h3[2 * c2 + 17] = leaky(bfhi(uhi));
        }

        float y0 = gbd2[0], y1 = gbd2[1], y2 = gbd2[2];
        #pragma unroll
        for (int k = 0; k < 32; ++k) {
            y0 = fmaf(gWd2[0 * 32 + k], h3[k], y0);
            y1 = fmaf(gWd2[1 * 32 + k], h3[k], y1);
            y2 = fmaf(gWd2[2 * 32 + k], h3[k], y2);
        }

        out[3 * row + 0] = fmaf(a0, y0, fmaf(c0, y1, fmaf(u0, y2, gbias[0])));
        out[3 * row + 1] = fmaf(a1, y0, fmaf(c1, y1, fmaf(u1, y2, gbias[1])));
        out[3 * row + 2] = fmaf(a2, y0, fmaf(c2, y1, fmaf(u2, y2, gbias[2])));
    }
}

extern "C" void kernel_launch(void* const* d_in, const int* in_sizes, int n_in,
                              void* d_out, int out_size, void* d_ws, size_t ws_size,
                              hipStream_t stream) {
    const float* v    = (const float*)d_in[0];
    const float* w    = (const float*)d_in[1];
    const float* W1   = (const float*)d_in[2];
    const float* b1   = (const float*)d_in[3];
    const float* W2   = (const float*)d_in[4];
    const float* b2   = (const float*)d_in[5];
    const float* Wd1  = (const float*)d_in[6];
    const float* bd1  = (const float*)d_in[7];
    const float* Wd2  = (const float*)d_in[8];
    const float* bd2  = (const float*)d_in[9];
    const float* bias = (const float*)d_in[10];

    const int nrows = in_sizes[0] / 3;
    dim3 block(256);
    dim3 grid((nrows + 255) / 256);
    hipLaunchKernelGGL(aero_mfma, grid, block, 0, stream,
                       v, w, W1, b1, W2, b2, Wd1, bd1, Wd2, bd2, bias,
                       (float*)d_out, nrows);
}